// Round 3
// baseline (558.819 us; speedup 1.0000x reference)
//
#include <hip/hip_runtime.h>
#include <hip/hip_bf16.h>

#define BB 64
#define KN 64
#define NPTS 32768
#define DD 2048
#define NCC 2048
#define NH 512
#define MM 4096   /* BB*KN */
#define K2 4096   /* 2*DD  */

typedef unsigned short u16;
typedef unsigned int u32;
typedef __attribute__((ext_vector_type(8))) short short8;
typedef __attribute__((ext_vector_type(4))) float f32x4;

__device__ __forceinline__ float bf2f(u32 u){
  union { u32 i; float f; } v; v.i = u << 16; return v.f;
}
__device__ __forceinline__ u16 f2bf(float f){
  union { float f; u32 i; } v; v.f = f;
  u32 x = v.i;
  return (u16)((x + 0x7fffu + ((x >> 16) & 1u)) >> 16);
}

// global_load_lds: per-lane global src, wave-uniform LDS base (+lane*16 by HW)
typedef __attribute__((address_space(3))) u32 as3_u32;
typedef const __attribute__((address_space(1))) u32 as1_u32;
__device__ __forceinline__ void glds16(const void* g, void* l){
  __builtin_amdgcn_global_load_lds((as1_u32*)g, (as3_u32*)l, 16, 0, 0);
}

// ---------------- fused prep: label count + used-cluster mark + weight transposes ----------------
// blocks [0,128): count labels; [128,640): transpose conv_w; [640,704): transpose w1;
// [704]: mark used clusters from knn labels.
__global__ __launch_bounds__(256) void k_prep(
    const int* __restrict__ labels, int* __restrict__ counts,
    const int* __restrict__ knn, int* __restrict__ used,
    const void* __restrict__ conv_w, u16* __restrict__ cwT, int fcw,
    const void* __restrict__ w1, u16* __restrict__ w1T, int fw1){
  __shared__ u16 tile[64][65];
  int bb = blockIdx.x, t = threadIdx.x;
  if(bb < 128){
    int n = bb*256 + t;
    atomicAdd(&counts[labels[n]], 1);
    return;
  }
  if(bb == 704){
    #pragma unroll
    for(int i=0;i<16;i++){
      int idx = i*256 + t;           // 4096 knn entries
      used[labels[knn[idx]]] = 1;    // benign race: all write 1
    }
    return;
  }
  const void* src; u16* dst; int Kd, Nd, isf32, tb;
  if(bb < 640){ src=conv_w; dst=cwT; Kd=K2; Nd=NH; isf32=fcw; tb=bb-128; }
  else        { src=w1;     dst=w1T; Kd=NH; Nd=NH; isf32=fw1; tb=bb-640; }
  int nbt = Nd >> 6;
  int k0 = (tb / nbt) << 6;
  int n0 = (tb % nbt) << 6;
  if(isf32){
    const float* s = (const float*)src;
    #pragma unroll
    for(int ph=0; ph<16; ph++){
      int idx = ph*256 + t;
      int r = idx >> 6, c = idx & 63;
      tile[r][c] = f2bf(s[(size_t)(k0+r)*Nd + n0 + c]);
    }
  } else {
    const u16* s = (const u16*)src;
    #pragma unroll
    for(int ph=0; ph<16; ph++){
      int idx = ph*256 + t;
      int r = idx >> 6, c = idx & 63;
      tile[r][c] = s[(size_t)(k0+r)*Nd + n0 + c];
    }
  }
  __syncthreads();
  #pragma unroll
  for(int ph=0; ph<16; ph++){
    int idx = ph*256 + t;
    int r = idx >> 6, c = idx & 63;
    dst[(size_t)(n0+r)*Kd + k0 + c] = tile[c][r];
  }
}

__global__ void k_scan(const int* __restrict__ counts, int* __restrict__ offsets){
  __shared__ int sb[256];
  int t = threadIdx.x;
  int c[8]; int s = 0;
  #pragma unroll
  for(int i=0;i<8;i++){ c[i] = counts[t*8+i]; s += c[i]; }
  sb[t] = s; __syncthreads();
  int v = s;
  for(int off=1; off<256; off<<=1){
    int u = (t>=off) ? sb[t-off] : 0;
    __syncthreads();
    v += u; sb[t] = v;
    __syncthreads();
  }
  int run = v - s;
  #pragma unroll
  for(int i=0;i<8;i++){ offsets[t*8+i] = run; run += c[i]; }
}

__global__ void k_scatter(const int* __restrict__ labels, const int* __restrict__ offsets,
                          int* __restrict__ cursor, int* __restrict__ sorted){
  int n = blockIdx.x*256 + threadIdx.x;
  int c = labels[n];
  int p = atomicAdd(&cursor[c], 1);
  sorted[offsets[c] + p] = n;
}

// ---------------- cluster means: LDS index prefetch, 2-row unroll, used-only ----------------
__global__ __launch_bounds__(256) void k_clumean(
    const void* __restrict__ feat, const int* __restrict__ counts,
    const int* __restrict__ offsets, const int* __restrict__ sorted,
    const int* __restrict__ used, int isf32, float* __restrict__ clu){
  int c = blockIdx.x, t = threadIdx.x;
  if(!used[c]) return;    // unused cluster means are never read
  __shared__ int ridx[64];
  int cnt = counts[c], start = offsets[c];
  float acc[8] = {0,0,0,0,0,0,0,0};
  for(int base=0; base<cnt; base+=64){
    int take = min(64, cnt-base);
    __syncthreads();
    if(t < take) ridx[t] = sorted[start+base+t];
    __syncthreads();
    if(isf32){
      const float* ff = (const float*)feat;
      int r = 0;
      for(; r+2<=take; r+=2){
        const float* p0 = ff + (size_t)ridx[r]*DD + t*8;
        const float* p1 = ff + (size_t)ridx[r+1]*DD + t*8;
        float4 a0=*(const float4*)p0, b0=*(const float4*)(p0+4);
        float4 a1=*(const float4*)p1, b1=*(const float4*)(p1+4);
        acc[0]+=a0.x+a1.x; acc[1]+=a0.y+a1.y; acc[2]+=a0.z+a1.z; acc[3]+=a0.w+a1.w;
        acc[4]+=b0.x+b1.x; acc[5]+=b0.y+b1.y; acc[6]+=b0.z+b1.z; acc[7]+=b0.w+b1.w;
      }
      if(r < take){
        const float* p0 = ff + (size_t)ridx[r]*DD + t*8;
        float4 a0=*(const float4*)p0, b0=*(const float4*)(p0+4);
        acc[0]+=a0.x; acc[1]+=a0.y; acc[2]+=a0.z; acc[3]+=a0.w;
        acc[4]+=b0.x; acc[5]+=b0.y; acc[6]+=b0.z; acc[7]+=b0.w;
      }
    } else {
      const u16* fb = (const u16*)feat;
      int r = 0;
      for(; r+2<=take; r+=2){
        const u16* p0 = fb + (size_t)ridx[r]*DD + t*8;
        const u16* p1 = fb + (size_t)ridx[r+1]*DD + t*8;
        uint4 v0 = *(const uint4*)p0, v1 = *(const uint4*)p1;
        acc[0]+=bf2f(v0.x&0xffffu)+bf2f(v1.x&0xffffu); acc[1]+=bf2f(v0.x>>16)+bf2f(v1.x>>16);
        acc[2]+=bf2f(v0.y&0xffffu)+bf2f(v1.y&0xffffu); acc[3]+=bf2f(v0.y>>16)+bf2f(v1.y>>16);
        acc[4]+=bf2f(v0.z&0xffffu)+bf2f(v1.z&0xffffu); acc[5]+=bf2f(v0.z>>16)+bf2f(v1.z>>16);
        acc[6]+=bf2f(v0.w&0xffffu)+bf2f(v1.w&0xffffu); acc[7]+=bf2f(v0.w>>16)+bf2f(v1.w>>16);
      }
      if(r < take){
        const u16* p0 = fb + (size_t)ridx[r]*DD + t*8;
        uint4 v0 = *(const uint4*)p0;
        acc[0]+=bf2f(v0.x&0xffffu); acc[1]+=bf2f(v0.x>>16);
        acc[2]+=bf2f(v0.y&0xffffu); acc[3]+=bf2f(v0.y>>16);
        acc[4]+=bf2f(v0.z&0xffffu); acc[5]+=bf2f(v0.z>>16);
        acc[6]+=bf2f(v0.w&0xffffu); acc[7]+=bf2f(v0.w>>16);
      }
    }
  }
  float div = fmaxf((float)cnt, 1.0f);
  float* o = clu + (size_t)c*DD + t*8;
  float4 o0 = make_float4(acc[0]/div, acc[1]/div, acc[2]/div, acc[3]/div);
  float4 o1 = make_float4(acc[4]/div, acc[5]/div, acc[6]/div, acc[7]/div);
  *(float4*)o = o0;
  *(float4*)(o+4) = o1;
}

// ---------------- partial A: block (b, dgroup g) accumulates 512 dims ----------------
__global__ __launch_bounds__(256) void k_Apart(
    const void* __restrict__ feat, const float* __restrict__ clu,
    const int* __restrict__ indexes, const int* __restrict__ labels,
    const int* __restrict__ knn, int isf32, float* __restrict__ Apart){
  int b = blockIdx.x >> 2, g = blockIdx.x & 3;
  int t = threadIdx.x;
  __shared__ float cfT[64][68];
  __shared__ int sl[64];
  if(t < 64) sl[t] = labels[knn[b*64 + t]];
  int qidx = indexes[b];
  __syncthreads();

  int i0 = (t & 15)*4, j0 = (t >> 4)*4;
  float acc[4][4];
  #pragma unroll
  for(int a=0;a<4;a++)
    #pragma unroll
    for(int c2=0;c2<4;c2++) acc[a][c2] = 0.f;

  for(int ch=g*8; ch<g*8+8; ch++){
    int dbase = ch*64;
    #pragma unroll
    for(int ps=0; ps<16; ps++){
      int idx = ps*256 + t;
      int k = idx >> 6, dd = idx & 63;
      float v;
      if(k == 0){
        size_t fi = (size_t)qidx*DD + dbase + dd;
        v = isf32 ? ((const float*)feat)[fi] : bf2f(((const u16*)feat)[fi]);
      } else {
        v = clu[(size_t)sl[k]*DD + dbase + dd];
      }
      cfT[dd][k] = v;
    }
    __syncthreads();
    #pragma unroll 4
    for(int dd=0; dd<64; dd++){
      float4 av = *(const float4*)&cfT[dd][i0];
      float4 bv = *(const float4*)&cfT[dd][j0];
      float aa[4] = {av.x, av.y, av.z, av.w};
      float bbv[4] = {bv.x, bv.y, bv.z, bv.w};
      #pragma unroll
      for(int ii=0;ii<4;ii++)
        #pragma unroll
        for(int jj=0;jj<4;jj++)
          acc[ii][jj] += aa[ii]*bbv[jj];
    }
    __syncthreads();
  }

  float* op = Apart + ((size_t)(g*64 + b))*4096;
  #pragma unroll
  for(int ii=0;ii<4;ii++)
    *(float4*)&op[(i0+ii)*64 + j0] = make_float4(acc[ii][0], acc[ii][1], acc[ii][2], acc[ii][3]);
}

// ---------------- final A: sum partials, keep mask, top-5, norms, adj ----------------
__global__ __launch_bounds__(256) void k_Afinal(
    const float* __restrict__ Apart, const int* __restrict__ labels,
    const int* __restrict__ knn,
    float* __restrict__ adj, float* __restrict__ norms){
  int b = blockIdx.x, t = threadIdx.x;
  __shared__ float A[64][65];
  __shared__ unsigned long long mb[64];
  __shared__ int sl[64];
  __shared__ int sk[64];
  if(t < 64) sl[t] = labels[knn[b*64 + t]];
  const float* P = Apart + (size_t)b*4096;
  const size_t gs = (size_t)64*4096;
  #pragma unroll
  for(int ps=0; ps<16; ps++){
    int idx = ps*256 + t;
    float s = P[idx] + P[idx+gs] + P[idx+2*gs] + P[idx+3*gs];
    A[idx>>6][idx&63] = s * 0.2f;
  }
  __syncthreads();
  if(t < 64){
    int dup = 0;
    for(int j=0;j<t;j++) dup |= (sl[j]==sl[t]);
    sk[t] = dup ? 0 : 1;
    unsigned long long chosen = 0;
    const float* row = A[t];
    #pragma unroll
    for(int p=0;p<5;p++){
      float best = -INFINITY; int bi = 0;
      for(int j=0;j<64;j++){
        bool taken = (chosen >> j) & 1ull;
        float v = row[j];
        if(!taken && v > best){ best = v; bi = j; }
      }
      chosen |= (1ull << bi);
    }
    mb[t] = chosen;
    norms[b*64+t] = sqrtf(fmaxf(A[t][t]*5.0f, 0.0f));
  }
  __syncthreads();
  float* O = adj + (size_t)b*4096;
  #pragma unroll
  for(int ps=0; ps<16; ps++){
    int idx = ps*256 + t;
    int i = idx >> 6, j = idx & 63;
    bool on = ((mb[i]>>j)&1ull) && ((mb[j]>>i)&1ull) && sk[i] && sk[j];
    O[idx] = on ? A[i][j] : 0.0f;
  }
}

// ---------------- fused x + agg: block (b, dquarter g); x slice in LDS, sparse agg ----------------
__global__ __launch_bounds__(256) void k_xagg(
    const void* __restrict__ feat, const float* __restrict__ clu,
    const int* __restrict__ indexes, const int* __restrict__ labels,
    const int* __restrict__ knn, const float* __restrict__ norms,
    const float* __restrict__ adj, int isf32, u16* __restrict__ xab){
  int b = blockIdx.x >> 2, g = blockIdx.x & 3;
  int t = threadIdx.x;
  __shared__ u16  xs[64][512];    // 64 KB bf16 x-slice
  __shared__ float adjs[64][65];  // 16.25 KB staged adj
  __shared__ float nzv[64][8];
  __shared__ u16   nzj[64][8];
  __shared__ int   nzc[64];
  __shared__ int   sl[64];
  __shared__ float sn[64];

  // stage adj tile (coalesced) + per-row meta
  const float* Ab = adj + (size_t)b*4096;
  #pragma unroll
  for(int ps=0; ps<16; ps++){
    int idx = ps*256 + t;
    adjs[idx>>6][idx&63] = Ab[idx];
  }
  if(t < 64){
    sl[t] = labels[knn[b*64 + t]];
    sn[t] = 1.0f / fmaxf(norms[b*64 + t], 1e-30f);
  }
  int qidx = indexes[b];
  int d = g*512 + t*2;                 // this thread's 2 dims
  float q0, q1;
  if(isf32){
    float2 qv = *(const float2*)((const float*)feat + (size_t)qidx*DD + d);
    q0 = qv.x; q1 = qv.y;
  } else {
    u32 w = *(const u32*)((const u16*)feat + (size_t)qidx*DD + d);
    q0 = bf2f(w & 0xffffu); q1 = bf2f(w >> 16);
  }
  __syncthreads();
  if(t < 64){                           // nonzero extraction from LDS adj row t
    int c = 0;
    for(int j=0;j<64;j++){
      float v = adjs[t][j];
      if(v != 0.0f && c < 8){ nzv[t][c] = v; nzj[t][c] = (u16)j; c++; }
    }
    nzc[t] = c;
  }
  float inv0 = sn[0];
  q0 *= inv0; q1 *= inv0;

  // phase 1: x rows (row 0 is zero), write LDS + global
  *(u32*)&xs[0][t*2] = 0u;
  *(u32*)(xab + (size_t)(b*64)*K2 + d) = 0u;
  for(int k=1;k<64;k++){
    float2 cv = *(const float2*)(clu + (size_t)sl[k]*DD + d);
    float invk = sn[k];
    u16 x0 = f2bf(cv.x*invk - q0), x1 = f2bf(cv.y*invk - q1);
    u32 w = (u32)x0 | ((u32)x1 << 16);
    *(u32*)&xs[k][t*2] = w;
    *(u32*)(xab + (size_t)(b*64+k)*K2 + d) = w;
  }
  __syncthreads();

  // phase 2: agg rows from sparse adj over LDS x
  for(int r=0;r<64;r++){
    float a0 = 0.f, a1 = 0.f;
    int c = nzc[r];
    for(int p=0;p<c;p++){
      float s = nzv[r][p]; int j = nzj[r][p];
      u32 w = *(const u32*)&xs[j][t*2];
      a0 += s*bf2f(w & 0xffffu);
      a1 += s*bf2f(w >> 16);
    }
    u32 w = (u32)f2bf(a0) | ((u32)f2bf(a1) << 16);
    *(u32*)(xab + (size_t)(b*64+r)*K2 + DD + d) = w;
  }
}

// ---------------- bf16 MFMA GEMM: C = epi(A @ Bt^T + bias), BM=BN=BK=64, 2 blocks/CU ----------------
template<int EPI>
__global__ __launch_bounds__(256, 2) void k_gemm(
    const u16* __restrict__ Am, const u16* __restrict__ Bt,
    const void* __restrict__ bias, const void* __restrict__ pa,
    int fbias, int fpa,
    void* __restrict__ Cout, int Md, int Nd, int Kd)
{
  __shared__ u16 As[2][64*64];
  __shared__ u16 Bs[2][64*64];
  int t = threadIdx.x;
  int nblk = gridDim.x;
  int bid = (blockIdx.x & 7)*(nblk >> 3) + (blockIdx.x >> 3);  // XCD chunking
  int nb = Nd >> 6;
  int m0 = (bid / nb) << 6;
  int n0 = (bid % nb) << 6;
  int wave = t >> 6, lane = t & 63;
  int wm = wave >> 1, wn = wave & 1;
  int lm = lane & 15, lq = lane >> 4;
  int lrow = lane >> 3, lcol = lane & 7;

  f32x4 acc[2][2];
  #pragma unroll
  for(int i=0;i<2;i++)
    #pragma unroll
    for(int j=0;j<2;j++) acc[i][j] = (f32x4){0.f,0.f,0.f,0.f};

  // LDS layout: linear [row][8 chunks of 16B]; logical chunk q at physical q^(row&7).
  // glds writes lane l at base+16*l, so the SOURCE carries the inverse swizzle.
  auto stage = [&](int buf, int kb){
    #pragma unroll
    for(int c=0;c<2;c++){
      int cb = wave*2 + c;              // 8 chunk-blocks of 8 rows (A)
      int row = cb*8 + lrow;
      int col = lcol ^ (row & 7);
      glds16(Am + (size_t)(m0+row)*Kd + kb + col*8, &As[buf][cb*512]);
    }
    #pragma unroll
    for(int c=0;c<2;c++){
      int cb = wave*2 + c;              // 8 chunk-blocks of 8 rows (B)
      int row = cb*8 + lrow;
      int col = lcol ^ (row & 7);
      glds16(Bt + (size_t)(n0+row)*Kd + kb + col*8, &Bs[buf][cb*512]);
    }
  };

  stage(0, 0);
  __syncthreads();
  int cur = 0;
  for(int kb=0; kb<Kd; kb+=64){
    if(kb + 64 < Kd) stage(cur^1, kb+64);   // prefetch stays in flight across compute
    #pragma unroll
    for(int kk=0;kk<2;kk++){
      short8 af[2], bfr[2];
      #pragma unroll
      for(int mi=0;mi<2;mi++){
        int r = wm*32 + mi*16 + lm;
        int p = ((kk<<2)+lq) ^ (r & 7);
        union{ uint4 u; short8 v; } x;
        x.u = *(const uint4*)&As[cur][r*64 + p*8];
        af[mi] = x.v;
      }
      #pragma unroll
      for(int ni=0;ni<2;ni++){
        int r = wn*32 + ni*16 + lm;
        int p = ((kk<<2)+lq) ^ (r & 7);
        union{ uint4 u; short8 v; } x;
        x.u = *(const uint4*)&Bs[cur][r*64 + p*8];
        bfr[ni] = x.v;
      }
      #pragma unroll
      for(int mi=0;mi<2;mi++)
        #pragma unroll
        for(int ni=0;ni<2;ni++)
          acc[mi][ni] = __builtin_amdgcn_mfma_f32_16x16x32_bf16(af[mi], bfr[ni], acc[mi][ni], 0, 0, 0);
    }
    __syncthreads();   // drains vmcnt (prefetch landed) + lgkmcnt
    cur ^= 1;
  }

  #pragma unroll
  for(int ni=0;ni<2;ni++){
    int col = n0 + wn*32 + ni*16 + lm;
    float bs = fbias ? ((const float*)bias)[col] : bf2f(((const u16*)bias)[col]);
    float av = 0.f;
    if(EPI==1) av = fpa ? ((const float*)pa)[col] : bf2f(((const u16*)pa)[col]);
    #pragma unroll
    for(int mi=0;mi<2;mi++){
      int rowb = m0 + wm*32 + mi*16 + lq*4;
      #pragma unroll
      for(int r2=0;r2<4;r2++){
        float v = acc[mi][ni][r2] + bs;
        if(EPI==0){
          v = fmaxf(v, 0.f);
          ((u16*)Cout)[(size_t)(rowb+r2)*Nd + col] = f2bf(v);
        } else {
          v = (v > 0.f) ? v : av*v;
          ((float*)Cout)[(size_t)(rowb+r2)*Nd + col] = v;
        }
      }
    }
  }
}

// ---------------- final: logits = h1 @ w2 + b2, softmax over 2 ----------------
__global__ __launch_bounds__(256) void k_out(
    const float* __restrict__ h1, const void* __restrict__ w2,
    const void* __restrict__ b2, int fw2, int fb2, int fo,
    void* __restrict__ out){
  int t = threadIdx.x; int lane = t & 63; int row = blockIdx.x*4 + (t >> 6);
  const float* hr = h1 + (size_t)row*NH;
  float s0 = 0.f, s1 = 0.f;
  #pragma unroll
  for(int j=0;j<NH/64;j++){
    int i = lane + j*64;
    float h = hr[i];
    float w0 = fw2 ? ((const float*)w2)[i*2+0] : bf2f(((const u16*)w2)[i*2+0]);
    float w1v= fw2 ? ((const float*)w2)[i*2+1] : bf2f(((const u16*)w2)[i*2+1]);
    s0 += h * w0;
    s1 += h * w1v;
  }
  #pragma unroll
  for(int off=32; off>0; off>>=1){
    s0 += __shfl_down(s0, off);
    s1 += __shfl_down(s1, off);
  }
  if(lane==0){
    float bb0 = fb2 ? ((const float*)b2)[0] : bf2f(((const u16*)b2)[0]);
    float bb1 = fb2 ? ((const float*)b2)[1] : bf2f(((const u16*)b2)[1]);
    float l0 = s0 + bb0;
    float l1 = s1 + bb1;
    float m = fmaxf(l0, l1);
    float e0 = expf(l0 - m), e1 = expf(l1 - m);
    float inv = 1.0f / (e0 + e1);
    if(fo){
      ((float*)out)[row*2+0] = e0*inv;
      ((float*)out)[row*2+1] = e1*inv;
    } else {
      ((u16*)out)[row*2+0] = f2bf(e0*inv);
      ((u16*)out)[row*2+1] = f2bf(e1*inv);
    }
  }
}

// ---------------- diagnostic sentinel: ws too small (~3.0 in either dtype) ----------------
__global__ void k_fill_sentinel(u32* __restrict__ out, int nwords){
  int i = blockIdx.x*256 + threadIdx.x;
  if(i < nwords) out[i] = 0x40404040u;
}

extern "C" void kernel_launch(void* const* d_in, const int* in_sizes, int n_in,
                              void* d_out, int out_size, void* d_ws, size_t ws_size,
                              hipStream_t stream) {
  const int* indexes = (const int*)d_in[0];
  const void* feat   = d_in[1];
  const int* labels  = (const int*)d_in[2];
  const int* knn     = (const int*)d_in[3];
  const void* conv_w = d_in[4];
  const void* conv_b = d_in[5];
  const void* w1     = d_in[6];
  const void* b1     = d_in[7];
  const void* pa     = d_in[8];
  const void* w2     = d_in[9];
  const void* b2     = d_in[10];

  // host-side dtype flags from byte sizes (default f32 unless exact bf16 size)
  int ff  = (in_sizes[1]  != (int)((size_t)NPTS*DD*2));
  int fcw = (in_sizes[4]  != (int)((size_t)2*DD*NH*2));
  int fcb = (in_sizes[5]  != NH*2);
  int fw1 = (in_sizes[6]  != (int)((size_t)NH*NH*2));
  int fb1 = (in_sizes[7]  != NH*2);
  int fpa = (in_sizes[8]  != NH*2);
  int fw2 = (in_sizes[9]  != NH*2*2);
  int fb2 = (in_sizes[10] != 2*2);
  int fo  = (out_size     != MM*2*2);

  char* w = (char*)d_ws;
  size_t o = 0;
  auto alloc = [&](size_t bytes) -> void* {
    void* p = w + o; o = (o + bytes + 255) & ~(size_t)255; return p;
  };
  int*   counts  = (int*)  alloc((size_t)NCC*4);
  int*   cursor  = (int*)  alloc((size_t)NCC*4);
  int*   used    = (int*)  alloc((size_t)NCC*4);
  int*   offsets = (int*)  alloc((size_t)NCC*4);
  int*   sorted  = (int*)  alloc((size_t)NPTS*4);
  float* norms   = (float*)alloc((size_t)MM*4);
  float* adj     = (float*)alloc((size_t)BB*64*64*4);
  float* Apart   = (float*)alloc((size_t)4*BB*64*64*4);  // 4 MB partial A
  float* clu     = (float*)alloc((size_t)NCC*DD*4);   // 16 MB; dead before GEMMs
  u16*   xab     = (u16*)  alloc((size_t)MM*K2*2);    // 32 MB
  u16*   cwT     = (u16*)  alloc((size_t)K2*NH*2);    // 4 MB
  u16*   w1T     = (u16*)  alloc((size_t)NH*NH*2);    // 0.5 MB
  u16*   hb      = (u16*)  clu;                       // alias: 4 MB
  float* h1      = (float*)((char*)clu + (size_t)MM*NH*2); // alias: 8 MB

  size_t NEED = o;
  if(ws_size < NEED){
    int nwords = out_size/4;
    k_fill_sentinel<<<(nwords+255)/256, 256, 0, stream>>>((u32*)d_out, nwords);
    return;
  }

  hipMemsetAsync(counts, 0, (size_t)NCC*4*3, stream);   // counts + cursor + used

  k_prep   <<<705, 256, 0, stream>>>(labels, counts, knn, used, conv_w, cwT, fcw, w1, w1T, fw1);
  k_scan   <<<1, 256, 0, stream>>>(counts, offsets);
  k_scatter<<<NPTS/256, 256, 0, stream>>>(labels, offsets, cursor, sorted);
  k_clumean<<<NCC, 256, 0, stream>>>(feat, counts, offsets, sorted, used, ff, clu);
  k_Apart  <<<BB*4, 256, 0, stream>>>(feat, clu, indexes, labels, knn, ff, Apart);
  k_Afinal <<<BB, 256, 0, stream>>>(Apart, labels, knn, adj, norms);
  k_xagg   <<<BB*4, 256, 0, stream>>>(feat, clu, indexes, labels, knn, norms, adj, ff, xab);

  k_gemm<0><<<(MM/64)*(NH/64), 256, 0, stream>>>(xab, cwT, conv_b, nullptr, fcb, 0, (void*)hb, MM, NH, K2);
  k_gemm<1><<<(MM/64)*(NH/64), 256, 0, stream>>>(hb, w1T, b1, pa, fb1, fpa, (void*)h1, MM, NH, NH);

  k_out    <<<MM/4, 256, 0, stream>>>(h1, w2, b2, fw2, fb2, fo, d_out);
}